// Round 4
// baseline (1322.023 us; speedup 1.0000x reference)
//
#include <hip/hip_runtime.h>
#include <cstdint>

#define T_LEN 1000
#define NB    256

__device__ __forceinline__ float rcpf_(float x)     { return __builtin_amdgcn_rcpf(x); }
__device__ __forceinline__ float sigmoidf_(float x) { return rcpf_(1.f + __expf(-x)); }
__device__ __forceinline__ float tanhf_(float x) {
    float e = __expf(2.f * x);
    return 1.f - 2.f * rcpf_(e + 1.f);
}
__device__ __forceinline__ float softplusf_(float x) {
    return fmaxf(x, 0.f) + __logf(1.f + __expf(-fabsf(x)));
}
__device__ __forceinline__ float bcast_(float v, int l) {
    return __uint_as_float(__builtin_amdgcn_readlane(__float_as_uint(v), l));
}

// ---------------- K1: gi2 = mini_batch @ W_ih2^T + b_ih2  -> out[b,t,0:30] (scratch) --------
__global__ __launch_bounds__(256) void gi2_kernel(
    const float* __restrict__ x, const float* __restrict__ W,
    const float* __restrict__ bias, float* __restrict__ out)
{
    __shared__ float xsT[100 * 67];          // xsT[k*67 + r], 26.8 KB

    const int tid = threadIdx.x;
    const int64_t base = (int64_t)blockIdx.x * (64 * 100);
    const float4* gx = (const float4*)(x + base);

#pragma unroll
    for (int it = 0; it < 7; ++it) {
        int i = tid + it * 256;
        if (i < 1600) {
            int r  = i / 25;
            int k4 = i - r * 25;
            float4 v = gx[i];                 // coalesced 16B/lane
            xsT[(4 * k4 + 0) * 67 + r] = v.x;
            xsT[(4 * k4 + 1) * 67 + r] = v.y;
            xsT[(4 * k4 + 2) * 67 + r] = v.z;
            xsT[(4 * k4 + 3) * 67 + r] = v.w;
        }
    }
    __syncthreads();

    const int lane = tid & 63;                               // row within tile
    const int wv   = __builtin_amdgcn_readfirstlane(tid >> 6);
    const int j0   = wv * 8;                                 // 8 output cols per wave

    float acc[8];
#pragma unroll
    for (int jj = 0; jj < 8; ++jj) acc[jj] = 0.f;

    for (int k = 0; k < 100; ++k) {
        float xv = xsT[k * 67 + lane];
#pragma unroll
        for (int jj = 0; jj < 8; ++jj) {
            int j = j0 + jj; j = j > 29 ? 29 : j;            // wave-uniform -> s_load
            acc[jj] = fmaf(xv, W[j * 100 + k], acc[jj]);
        }
    }
    float* orow = out + base + (int64_t)lane * 100;
#pragma unroll
    for (int jj = 0; jj < 8; ++jj) {
        int j = j0 + jj;
        if (j < 30) orow[j] = acc[jj] + bias[j];
    }
}

// ---------------- K2: sequential scan. ONE WAVE per batch element, ZERO barriers ------------
// All handoffs via v_readlane; only the 100-wide z vector goes through LDS (same-wave
// in-order write->read). Emitter (lagged 1 step) fills the LDS latency window. Global
// prefetch distance 2 via manual unroll-by-2 (use-then-overwrite registers, no movs).
// No __syncthreads anywhere in the loop => prefetch loads / output stores never drained.

#define EMIT_STEP(S, G2Pn)                                               \
    do {                                                                 \
        float ea_ = be1r, eb_ = 0.f;                                     \
        _Pragma("unroll")                                                \
        for (int k_ = 0; k_ < 5; ++k_) {                                 \
            ea_ = fmaf(we1r[2*k_],        sh1_[2*k_],     ea_);          \
            eb_ = fmaf(we1r[2*k_+1],      sh1_[2*k_+1],   eb_);          \
            ea_ = fmaf(we1r[10+2*k_],     (G2Pn)[2*k_],   ea_);          \
            eb_ = fmaf(we1r[10+2*k_+1],   (G2Pn)[2*k_+1], eb_);          \
        }                                                                \
        float e1v_ = fmaxf(ea_ + eb_, 0.f);                              \
        float se1_[20];                                                  \
        _Pragma("unroll")                                                \
        for (int l_ = 0; l_ < 20; ++l_) se1_[l_] = bcast_(e1v_, l_);     \
        float fa_ = be2r, fb_ = 0.f;                                     \
        _Pragma("unroll")                                                \
        for (int k_ = 0; k_ < 10; ++k_) {                                \
            fa_ = fmaf(we2r[2*k_],   se1_[2*k_],   fa_);                 \
            fb_ = fmaf(we2r[2*k_+1], se1_[2*k_+1], fb_);                 \
        }                                                                \
        float e2v_ = fmaxf(fa_ + fb_, 0.f);                              \
        float se2_[20];                                                  \
        _Pragma("unroll")                                                \
        for (int l_ = 0; l_ < 20; ++l_) se2_[l_] = bcast_(e2v_, l_);     \
        float xa0_ = be3A, xa1_ = 0.f, xb0_ = be3B, xb1_ = 0.f;          \
        _Pragma("unroll")                                                \
        for (int l_ = 0; l_ < 10; ++l_) {                                \
            xa0_ = fmaf(we3A[2*l_],   se2_[2*l_],   xa0_);               \
            xa1_ = fmaf(we3A[2*l_+1], se2_[2*l_+1], xa1_);               \
            xb0_ = fmaf(we3B[2*l_],   se2_[2*l_],   xb0_);               \
            xb1_ = fmaf(we3B[2*l_+1], se2_[2*l_+1], xb1_);               \
        }                                                                \
        float xA_ = sigmoidf_(xa0_ + xa1_);                              \
        float xB_ = sigmoidf_(xb0_ + xb1_);                              \
        if (lane < 50) {                                                 \
            int64_t ro_ = rowbase + (int64_t)(S) * 100;                  \
            out[ro_ + lane]      = xA_;                                  \
            out[ro_ + lane + 50] = xB_;                                  \
        }                                                                \
    } while (0)

#define STEP_BODY(T, EA, EB, GC, G2C, G2P)                               \
    do {                                                                 \
        float ha_ = bt1r, hb_ = 0.f, ga_ = bhh1r, gb_ = 0.f;             \
        _Pragma("unroll")                                                \
        for (int k_ = 0; k_ < 5; ++k_) {                                 \
            ha_ = fmaf(wt1r[2*k_],    sh1_[2*k_],   ha_);                \
            hb_ = fmaf(wt1r[2*k_+1],  sh1_[2*k_+1], hb_);                \
            ga_ = fmaf(whh1r[2*k_],   sh1_[2*k_],   ga_);                \
            gb_ = fmaf(whh1r[2*k_+1], sh1_[2*k_+1], gb_);                \
        }                                                                \
        float hidv_ = fmaxf(ha_ + hb_, 0.f);                             \
        float gh1v_ = ga_ + gb_;                                         \
        float sgh_[20];                                                  \
        _Pragma("unroll")                                                \
        for (int l_ = 0; l_ < 20; ++l_) sgh_[l_] = bcast_(hidv_, l_);    \
        float sA0_ = bscx, sA1_ = 0.f, sB0_ = bscy, sB1_ = 0.f;          \
        float q0_ = dr, q1_ = 0.f;                                       \
        _Pragma("unroll")                                                \
        for (int l_ = 0; l_ < 10; ++l_) {                                \
            sA0_ = fmaf(wscA[2*l_],   sgh_[2*l_],   sA0_);               \
            sA1_ = fmaf(wscA[2*l_+1], sgh_[2*l_+1], sA1_);               \
            sB0_ = fmaf(wscB[2*l_],   sgh_[2*l_],   sB0_);               \
            sB1_ = fmaf(wscB[2*l_+1], sgh_[2*l_+1], sB1_);               \
            q0_  = fmaf(Cr[2*l_],     sgh_[2*l_],   q0_);                \
            q1_  = fmaf(Cr[2*l_+1],   sgh_[2*l_+1], q1_);                \
        }                                                                \
        float gq_ = q0_ + q1_;                                           \
        float zA_ = softplusf_(sA0_ + sA1_) * (EA);                      \
        float zB_ = softplusf_(sB0_ + sB1_) * (EB);                      \
        if (lane < 50) { ss[lane] = zA_; ss[52 + lane] = zB_; }          \
        {                                                                \
            int tp_ = (T) + 2 < T_LEN ? (T) + 2 : T_LEN - 1;             \
            const float* ep_ = erow + (int64_t)tp_ * 100;                \
            (EA) = ep_[ls];                                              \
            (EB) = ep_[ls + 50];                                         \
        }                                                                \
        float g2a_ = bhh2r, g2b_ = 0.f;                                  \
        _Pragma("unroll")                                                \
        for (int k_ = 0; k_ < 5; ++k_) {                                 \
            g2a_ = fmaf(whh2r[2*k_],   (G2C)[2*k_],   g2a_);             \
            g2b_ = fmaf(whh2r[2*k_+1], (G2C)[2*k_+1], g2b_);             \
        }                                                                \
        float gh2v_ = g2a_ + g2b_;                                       \
        float gi2v_ = (GC);                                              \
        {                                                                \
            int tp_ = (T) + 2 < T_LEN ? (T) + 2 : T_LEN - 1;             \
            (GC) = out[rowbase + (int64_t)tp_ * 100 + l30];              \
        }                                                                \
        float a2_   = gi2v_ + gh2v_;                                     \
        float a210_ = __shfl(a2_,   lane + 10);                          \
        float g2in_ = __shfl(gi2v_, lane + 20);                          \
        float g2hn_ = __shfl(gh2v_, lane + 20);                          \
        if (lane < 10) {                                                 \
            float r_ = sigmoidf_(a2_);                                   \
            float u_ = sigmoidf_(a210_);                                 \
            float n_ = tanhf_(fmaf(r_, g2hn_, g2in_));                   \
            h2keep = fmaf(u_, h2keep - n_, n_);                          \
        }                                                                \
        if ((T) >= 1) EMIT_STEP((T) - 1, G2P);                           \
        __builtin_amdgcn_wave_barrier();                                 \
        {                                                                \
            const float4* sp4_ = (const float4*)(&ss[52 * h]);           \
            float p0_ = 0.f, p1_ = 0.f, p2_ = 0.f, p3_ = 0.f;            \
            _Pragma("unroll")                                            \
            for (int c_ = 0; c_ < 13; ++c_) {                            \
                float4 v_ = sp4_[c_];                                    \
                p0_ = fmaf(wbig[4*c_+0], v_.x, p0_);                     \
                p1_ = fmaf(wbig[4*c_+1], v_.y, p1_);                     \
                p2_ = fmaf(wbig[4*c_+2], v_.z, p2_);                     \
                p3_ = fmaf(wbig[4*c_+3], v_.w, p3_);                     \
            }                                                            \
            float p_ = (p0_ + p1_) + (p2_ + p3_);                        \
            float gi1v_ = p_ + __shfl_xor(p_, 32) + br1 + gq_;           \
            float av_   = gi1v_ + gh1v_;                                 \
            float a110_ = __shfl(av_,   lane + 10);                      \
            float g1in_ = __shfl(gi1v_, lane + 20);                      \
            float g1hn_ = __shfl(gh1v_, lane + 20);                      \
            if (lane < 10) {                                             \
                float r_ = sigmoidf_(av_);                               \
                float u_ = sigmoidf_(a110_);                             \
                float n_ = tanhf_(fmaf(r_, g1hn_, g1in_));               \
                h1keep = fmaf(u_, h1keep - n_, n_);                      \
            }                                                            \
        }                                                                \
        _Pragma("unroll")                                                \
        for (int k_ = 0; k_ < 10; ++k_) {                                \
            sh1_[k_]  = bcast_(h1keep, k_);                              \
            (G2P)[k_] = bcast_(h2keep, k_);                              \
        }                                                                \
    } while (0)

__global__ __launch_bounds__(64) void scan_kernel(
    const float* __restrict__ eps,
    const float* __restrict__ W_ih1, const float* __restrict__ W_hh1,
    const float* __restrict__ b_ih1, const float* __restrict__ b_hh1,
    const float* __restrict__ W_hh2, const float* __restrict__ b_hh2,
    const float* __restrict__ h1_0,  const float* __restrict__ h2_0,
    const float* __restrict__ Wt1,   const float* __restrict__ bt1,
    const float* __restrict__ Wloc,  const float* __restrict__ bloc,
    const float* __restrict__ Wsc,   const float* __restrict__ bsc,
    const float* __restrict__ We1,   const float* __restrict__ be1,
    const float* __restrict__ We2,   const float* __restrict__ be2,
    const float* __restrict__ We3,   const float* __restrict__ be3,
    float* out)
{
    __shared__ __align__(16) float ss[104];          // z-tilde, two padded halves

    const int lane = threadIdx.x;                    // 0..63, single wave
    const int64_t rowbase = (int64_t)blockIdx.x * (T_LEN * 100);

    const int j   = lane & 31;
    const int jc  = j < 30 ? j : 29;       // gi1/gh1 output row
    const int h   = lane >> 5;             // k-half for the 100-deep gi1 reduction
    const int lt  = lane < 20 ? lane : 19; // hid / emitter-hidden rows
    const int ls  = lane < 50 ? lane : 49; // z / output columns
    const int l30 = lane < 30 ? lane : 29; // h2 gate rows

    // ---- per-lane weights (multi-role; ~222 VGPRs) ----
    float wt1r[10], whh1r[10], whh2r[10];
    float wscA[20], wscB[20], Cr[20], we1r[20], we2r[20], we3A[20], we3B[20];
    float wbig[52];

#pragma unroll
    for (int k = 0; k < 10; ++k) {
        wt1r[k]  = Wt1[lt * 10 + k];
        whh1r[k] = W_hh1[jc * 10 + k];
        whh2r[k] = W_hh2[l30 * 10 + k];
    }
    float bt1r = bt1[lt], bhh1r = b_hh1[jc], br1 = b_ih1[jc], bhh2r = b_hh2[l30];
#pragma unroll
    for (int l = 0; l < 20; ++l) {
        wscA[l] = Wsc[ls * 20 + l];
        wscB[l] = Wsc[(ls + 50) * 20 + l];
        we1r[l] = We1[lt * 20 + l];
        we2r[l] = We2[lt * 20 + l];
        we3A[l] = We3[ls * 20 + l];
        we3B[l] = We3[(ls + 50) * 20 + l];
    }
    float bscx = bsc[ls], bscy = bsc[ls + 50];
    float be1r = be1[lt], be2r = be2[lt];
    float be3A = be3[ls], be3B = be3[ls + 50];
#pragma unroll
    for (int i = 0; i < 50; ++i) wbig[i] = W_ih1[jc * 100 + h * 50 + i];
    wbig[50] = 0.f; wbig[51] = 0.f;

    // one-off fold: Cr[l] = (W_ih1 @ Wloc)[jc][l],  dr = (W_ih1 @ bloc)[jc]
    float dr = 0.f;
#pragma unroll
    for (int l = 0; l < 20; ++l) Cr[l] = 0.f;
    for (int kk = 0; kk < 100; ++kk) {
        float w = W_ih1[jc * 100 + kk];
        dr = fmaf(w, bloc[kk], dr);
#pragma unroll
        for (int l = 0; l < 20; ++l) Cr[l] = fmaf(w, Wloc[kk * 20 + l], Cr[l]);
    }

    if (lane < 2) { ss[50 + lane] = 0.f; ss[102 + lane] = 0.f; }   // zero float4 pads

    // ---- recurrent state ----
    float h1keep = h1_0[lane < 10 ? lane : 0];
    float h2keep = h2_0[lane < 10 ? lane : 0];
    float sh1_[10], g2U[10], g2V[10];
#pragma unroll
    for (int k = 0; k < 10; ++k) {
        sh1_[k] = h1_0[k];
        g2U[k]  = h2_0[k];
        g2V[k]  = h2_0[k];
    }

    // ---- distance-2 prefetch buffers ----
    const float* erow = eps + rowbase;
    float eA0 = erow[ls],       eB0 = erow[ls + 50];
    float eA1 = erow[100 + ls], eB1 = erow[100 + ls + 50];
    float gC0 = out[rowbase + l30];
    float gC1 = out[rowbase + 100 + l30];

#pragma unroll 1
    for (int tt = 0; tt < T_LEN; tt += 2) {
        STEP_BODY(tt,     eA0, eB0, gC0, g2U, g2V);
        STEP_BODY(tt + 1, eA1, eB1, gC1, g2V, g2U);
    }
    // lagged final emitter: h1n(999)=sh1_, H2 = h2_seq[998] = g2V
    EMIT_STEP(T_LEN - 1, g2V);
}

extern "C" void kernel_launch(void* const* d_in, const int* in_sizes, int n_in,
                              void* d_out, int out_size, void* d_ws, size_t ws_size,
                              hipStream_t stream) {
    const float* mini_batch = (const float*)d_in[0];
    const float* eps        = (const float*)d_in[1];
    const float* W_ih1      = (const float*)d_in[2];
    const float* W_hh1      = (const float*)d_in[3];
    const float* b_ih1      = (const float*)d_in[4];
    const float* b_hh1      = (const float*)d_in[5];
    const float* W_ih2      = (const float*)d_in[6];
    const float* W_hh2      = (const float*)d_in[7];
    const float* b_ih2      = (const float*)d_in[8];
    const float* b_hh2      = (const float*)d_in[9];
    const float* h1_0       = (const float*)d_in[10];
    const float* h2_0       = (const float*)d_in[11];
    const float* Wt1        = (const float*)d_in[12];
    const float* bt1        = (const float*)d_in[13];
    const float* Wloc       = (const float*)d_in[14];
    const float* bloc       = (const float*)d_in[15];
    const float* Wsc        = (const float*)d_in[16];
    const float* bsc        = (const float*)d_in[17];
    const float* We1        = (const float*)d_in[18];
    const float* be1        = (const float*)d_in[19];
    const float* We2        = (const float*)d_in[20];
    const float* be2        = (const float*)d_in[21];
    const float* We3        = (const float*)d_in[22];
    const float* be3        = (const float*)d_in[23];
    float* out = (float*)d_out;

    // K1: gi2 precompute into out[.., 0:30] (scratch region, overwritten later by K2)
    gi2_kernel<<<(NB * T_LEN) / 64, 256, 0, stream>>>(mini_batch, W_ih2, b_ih2, out);

    // K2: sequential scan, one single-wave block per batch element, zero barriers
    scan_kernel<<<NB, 64, 0, stream>>>(eps, W_ih1, W_hh1, b_ih1, b_hh1, W_hh2, b_hh2,
                                       h1_0, h2_0, Wt1, bt1, Wloc, bloc, Wsc, bsc,
                                       We1, be1, We2, be2, We3, be3, out);
}

// Round 5
// 834.020 us; speedup vs baseline: 1.5851x; 1.5851x over previous
//
#include <hip/hip_runtime.h>
#include <cstdint>

#define T_LEN 1000
#define NB    256

__device__ __forceinline__ float rcpf_(float x)     { return __builtin_amdgcn_rcpf(x); }
__device__ __forceinline__ float sigmoidf_(float x) { return rcpf_(1.f + __expf(-x)); }
__device__ __forceinline__ float tanhf_(float x) {
    float e = __expf(2.f * x);
    return 1.f - 2.f * rcpf_(e + 1.f);
}
__device__ __forceinline__ float softplusf_(float x) {
    return fmaxf(x, 0.f) + __logf(1.f + __expf(-fabsf(x)));
}
__device__ __forceinline__ float bcast_(float v, int l) {
    return __uint_as_float(__builtin_amdgcn_readlane(__float_as_uint(v), l));
}

// Raw barrier WITHOUT vmcnt drain: orders LDS (lgkmcnt(0)) + rendezvous, but leaves
// global prefetch loads / output stores in flight across the barrier (T3/T4 mechanism).
#define BARRIER_SYNC() asm volatile("s_waitcnt lgkmcnt(0)\n\ts_barrier" ::: "memory")

// ---------------- K1: gi2 = mini_batch @ W_ih2^T + b_ih2  -> out[b,t,0:30] (scratch) --------
__global__ __launch_bounds__(256) void gi2_kernel(
    const float* __restrict__ x, const float* __restrict__ W,
    const float* __restrict__ bias, float* __restrict__ out)
{
    __shared__ float xsT[100 * 67];          // xsT[k*67 + r], 26.8 KB

    const int tid = threadIdx.x;
    const int64_t base = (int64_t)blockIdx.x * (64 * 100);
    const float4* gx = (const float4*)(x + base);

#pragma unroll
    for (int it = 0; it < 7; ++it) {
        int i = tid + it * 256;
        if (i < 1600) {
            int r  = i / 25;
            int k4 = i - r * 25;
            float4 v = gx[i];                 // coalesced 16B/lane
            xsT[(4 * k4 + 0) * 67 + r] = v.x;
            xsT[(4 * k4 + 1) * 67 + r] = v.y;
            xsT[(4 * k4 + 2) * 67 + r] = v.z;
            xsT[(4 * k4 + 3) * 67 + r] = v.w;
        }
    }
    __syncthreads();

    const int lane = tid & 63;                               // row within tile
    const int wv   = __builtin_amdgcn_readfirstlane(tid >> 6);
    const int j0   = wv * 8;                                 // 8 output cols per wave

    float acc[8];
#pragma unroll
    for (int jj = 0; jj < 8; ++jj) acc[jj] = 0.f;

    for (int k = 0; k < 100; ++k) {
        float xv = xsT[k * 67 + lane];
#pragma unroll
        for (int jj = 0; jj < 8; ++jj) {
            int j = j0 + jj; j = j > 29 ? 29 : j;            // wave-uniform -> s_load
            acc[jj] = fmaf(xv, W[j * 100 + k], acc[jj]);
        }
    }
    float* orow = out + base + (int64_t)lane * 100;
#pragma unroll
    for (int jj = 0; jj < 8; ++jj) {
        int j = j0 + jj;
        if (j < 30) orow[j] = acc[jj] + bias[j];
    }
}

// ---------------- K2: sequential scan. 1 block / batch element, 2 waves ---------------------
// wave0: h1 critical chain.  wave1: h2 GRU + emitter (lagged 1 step) + stores.
// Per-step sync is a raw lgkmcnt(0)+s_barrier (no vmcnt drain); eps/gi2 prefetch distance 2
// stays in flight across barriers, hiding the ~900cy HBM latency.
__global__ __launch_bounds__(128) void scan_kernel(
    const float* __restrict__ eps,
    const float* __restrict__ W_ih1, const float* __restrict__ W_hh1,
    const float* __restrict__ b_ih1, const float* __restrict__ b_hh1,
    const float* __restrict__ W_hh2, const float* __restrict__ b_hh2,
    const float* __restrict__ h1_0,  const float* __restrict__ h2_0,
    const float* __restrict__ Wt1,   const float* __restrict__ bt1,
    const float* __restrict__ Wloc,  const float* __restrict__ bloc,
    const float* __restrict__ Wsc,   const float* __restrict__ bsc,
    const float* __restrict__ We1,   const float* __restrict__ be1,
    const float* __restrict__ We2,   const float* __restrict__ be2,
    const float* __restrict__ We3,   const float* __restrict__ be3,
    float* out)
{
    __shared__ __align__(16) float ss2[2][52];       // z-tilde halves (pads zeroed), wave0-private
    __shared__ __align__(16) float sh1ring[2][12];   // h1 after step t -> slot t&1 (w0 -> w1)

    const int lane = threadIdx.x & 63;
    const int64_t rowbase = (int64_t)blockIdx.x * T_LEN * 100;
    const int wave = __builtin_amdgcn_readfirstlane((int)(threadIdx.x >> 6));

    if (wave == 0) {
        // ================= wave0: h1 chain =================
        const int j  = lane & 31;
        const int jc = j < 30 ? j : 29;        // clamped row (garbage lanes unused)
        const int h  = lane >> 5;              // k-half for the 100-deep gi1 reduction
        const int lt = lane < 20 ? lane : 19;
        const int ls = lane < 50 ? lane : 49;

        float wt1r[10], whh1r[10], wscA[20], wscB[20], wbig[52], Cr[20];
#pragma unroll
        for (int k = 0; k < 10; ++k) {
            wt1r[k]  = Wt1[lt * 10 + k];
            whh1r[k] = W_hh1[jc * 10 + k];
        }
        float bt1r  = bt1[lt];
        float bhh1r = b_hh1[jc];
        float br1   = b_ih1[jc];
#pragma unroll
        for (int l = 0; l < 20; ++l) {
            wscA[l] = Wsc[ls * 20 + l];
            wscB[l] = Wsc[(ls + 50) * 20 + l];
        }
        float bscA = bsc[ls], bscB = bsc[ls + 50];
#pragma unroll
        for (int i = 0; i < 50; ++i) wbig[i] = W_ih1[jc * 100 + h * 50 + i];
        wbig[50] = 0.f; wbig[51] = 0.f;

        // one-off fold: Cr[l] = (W_ih1 @ Wloc)[jc][l],  dr = (W_ih1 @ bloc)[jc]
        float dr = 0.f;
#pragma unroll
        for (int l = 0; l < 20; ++l) Cr[l] = 0.f;
        for (int kk = 0; kk < 100; ++kk) {
            float w = W_ih1[jc * 100 + kk];
            dr = fmaf(w, bloc[kk], dr);
#pragma unroll
            for (int l = 0; l < 20; ++l) Cr[l] = fmaf(w, Wloc[kk * 20 + l], Cr[l]);
        }

        if (lane < 2) { ss2[0][50 + lane] = 0.f; ss2[1][50 + lane] = 0.f; }

        float h1keep = h1_0[lane < 10 ? lane : 0];   // per-lane own h1[j] (lanes 0..9)
        float sh1_[10];
#pragma unroll
        for (int k = 0; k < 10; ++k) sh1_[k] = h1_0[k];   // uniform -> SGPRs

        const float* erow = eps + rowbase;
        float eA0 = erow[ls],        eB0 = erow[ls + 50];
        float eA1 = erow[100 + ls],  eB1 = erow[100 + ls + 50];

#pragma unroll 1
        for (int t = 0; t <= T_LEN; ++t) {
            if (t < T_LEN) {
                // issue eps(t+2) prefetch FIRST (distance 2, never drained)
                const int tp = t + 2 < T_LEN ? t + 2 : T_LEN - 1;
                float eAf = erow[(int64_t)tp * 100 + ls];
                float eBf = erow[(int64_t)tp * 100 + ls + 50];

                // hid + gh1 from SGPR-resident h1 (2 accumulators each)
                float ha = bt1r, hb = 0.f, ga = bhh1r, gb = 0.f;
#pragma unroll
                for (int k = 0; k < 5; ++k) {
                    ha = fmaf(wt1r[2 * k],      sh1_[2 * k],     ha);
                    hb = fmaf(wt1r[2 * k + 1],  sh1_[2 * k + 1], hb);
                    ga = fmaf(whh1r[2 * k],     sh1_[2 * k],     ga);
                    gb = fmaf(whh1r[2 * k + 1], sh1_[2 * k + 1], gb);
                }
                float hidv = fmaxf(ha + hb, 0.f);
                float gh1v = ga + gb;

                float sgh[20];
#pragma unroll
                for (int l = 0; l < 20; ++l) sgh[l] = bcast_(hidv, l);

                // sc pair + folded loc term gq (2 accumulators per chain)
                float sA0 = bscA, sA1 = 0.f, sB0 = bscB, sB1 = 0.f, q0 = dr, q1 = 0.f;
#pragma unroll
                for (int l = 0; l < 10; ++l) {
                    sA0 = fmaf(wscA[2 * l],     sgh[2 * l],     sA0);
                    sA1 = fmaf(wscA[2 * l + 1], sgh[2 * l + 1], sA1);
                    sB0 = fmaf(wscB[2 * l],     sgh[2 * l],     sB0);
                    sB1 = fmaf(wscB[2 * l + 1], sgh[2 * l + 1], sB1);
                    q0  = fmaf(Cr[2 * l],       sgh[2 * l],     q0);
                    q1  = fmaf(Cr[2 * l + 1],   sgh[2 * l + 1], q1);
                }
                float gq = q0 + q1;
                float zA = softplusf_(sA0 + sA1) * eA0;
                float zB = softplusf_(sB0 + sB1) * eB0;
                if (lane < 50) { ss2[0][lane] = zA; ss2[1][lane] = zB; }

                // rotate prefetch regs (use-then-overwrite)
                eA0 = eA1; eB0 = eB1; eA1 = eAf; eB1 = eBf;

                __builtin_amdgcn_wave_barrier();

                // gi1 partial: 50-deep dot over own k-half, 4 accumulators
                const float4* sp4 = (const float4*)(&ss2[h][0]);
                float p0 = 0.f, p1 = 0.f, p2 = 0.f, p3 = 0.f;
#pragma unroll
                for (int c = 0; c < 13; ++c) {
                    float4 v = sp4[c];
                    p0 = fmaf(wbig[4 * c + 0], v.x, p0);
                    p1 = fmaf(wbig[4 * c + 1], v.y, p1);
                    p2 = fmaf(wbig[4 * c + 2], v.z, p2);
                    p3 = fmaf(wbig[4 * c + 3], v.w, p3);
                }
                float p = (p0 + p1) + (p2 + p3);
                float gi1v = p + __shfl_xor(p, 32) + br1 + gq;
                float av   = gi1v + gh1v;
                float a10  = __shfl(av,   lane + 10);
                float gin  = __shfl(gi1v, lane + 20);
                float ghn  = __shfl(gh1v, lane + 20);
                if (lane < 10) {
                    float r = sigmoidf_(av);
                    float u = sigmoidf_(a10);
                    float n = tanhf_(fmaf(r, ghn, gin));
                    h1keep = fmaf(u, h1keep - n, n);       // (1-u)*n + u*h1
                    sh1ring[t & 1][lane] = h1keep;          // hand-off to wave1
                }
#pragma unroll
                for (int k = 0; k < 10; ++k) sh1_[k] = bcast_(h1keep, k);
            }
            BARRIER_SYNC();
        }
    } else {
        // ================= wave1: h2 chain (SGPR state) + emitter(t-1) =================
        const int lt20 = lane < 20 ? lane : 19;
        const int l30  = lane < 30 ? lane : 29;
        const int ls   = lane < 50 ? lane : 49;

        float whh2r[10];
#pragma unroll
        for (int k = 0; k < 10; ++k) whh2r[k] = W_hh2[l30 * 10 + k];
        float bhh2r = b_hh2[l30];

        float we1r[20], we2r[20], we3A[20], we3B[20];
#pragma unroll
        for (int k = 0; k < 20; ++k) {
            we1r[k] = We1[lt20 * 20 + k];
            we2r[k] = We2[lt20 * 20 + k];
            we3A[k] = We3[ls * 20 + k];
            we3B[k] = We3[(ls + 50) * 20 + k];
        }
        float be1r = be1[lt20], be2r = be2[lt20];
        float be3A = be3[ls],   be3B = be3[ls + 50];

        float h2keep = h2_0[lane < 10 ? lane : 0];
        float g2c[10], g2p[10];                  // H2(t), H2(t-1) as broadcast scalars
#pragma unroll
        for (int k = 0; k < 10; ++k) { g2c[k] = h2_0[k]; g2p[k] = h2_0[k]; }

        float gcur = out[rowbase + l30];                 // gi2(0)
        float gnxt = out[rowbase + 100 + l30];           // gi2(1)

#pragma unroll 1
        for (int t = 0; t <= T_LEN; ++t) {
            // issue gi2(t+2) prefetch FIRST (distance 2, never drained)
            const int tp = t + 2 < T_LEN ? t + 2 : T_LEN - 1;
            float gfut = out[rowbase + (int64_t)tp * 100 + l30];

            // early h1(t-1) read for emitter (latency hidden under h2 GRU)
            float4 d0 = make_float4(0.f, 0.f, 0.f, 0.f);
            float4 d1 = d0; float d8 = 0.f, d9 = 0.f;
            if (t >= 1) {
                const int s1 = (t - 1) & 1;
                d0 = *(const float4*)(&sh1ring[s1][0]);
                d1 = *(const float4*)(&sh1ring[s1][4]);
                d8 = sh1ring[s1][8]; d9 = sh1ring[s1][9];
            }

            const bool upd = (t < T_LEN);
            if (upd) {
                float ga = bhh2r, gb = 0.f;
#pragma unroll
                for (int k = 0; k < 5; ++k) {
                    ga = fmaf(whh2r[2 * k],     g2c[2 * k],     ga);
                    gb = fmaf(whh2r[2 * k + 1], g2c[2 * k + 1], gb);
                }
                float gh2v = ga + gb;
                float gi2v = gcur;
                gcur = gnxt; gnxt = gfut;
                float a2  = gi2v + gh2v;
                float a10 = __shfl(a2,   lane + 10);
                float gin = __shfl(gi2v, lane + 20);
                float ghn = __shfl(gh2v, lane + 20);
                if (lane < 10) {
                    float r = sigmoidf_(a2);
                    float u = sigmoidf_(a10);
                    float n = tanhf_(fmaf(r, ghn, gin));
                    h2keep = fmaf(u, h2keep - n, n);       // H2(t+1)
                }
            }

            if (t >= 1) {
                // emitter step s = t-1: h1(s) from LDS, H2(s)=g2p broadcast
                float ea = be1r, eb = 0.f;
                ea = fmaf(we1r[0], d0.x, ea); eb = fmaf(we1r[1], d0.y, eb);
                ea = fmaf(we1r[2], d0.z, ea); eb = fmaf(we1r[3], d0.w, eb);
                ea = fmaf(we1r[4], d1.x, ea); eb = fmaf(we1r[5], d1.y, eb);
                ea = fmaf(we1r[6], d1.z, ea); eb = fmaf(we1r[7], d1.w, eb);
                ea = fmaf(we1r[8], d8,   ea); eb = fmaf(we1r[9], d9,   eb);
#pragma unroll
                for (int k = 0; k < 5; ++k) {
                    ea = fmaf(we1r[10 + 2 * k],     g2p[2 * k],     ea);
                    eb = fmaf(we1r[10 + 2 * k + 1], g2p[2 * k + 1], eb);
                }
                float e1v = fmaxf(ea + eb, 0.f);

                float se1v[20];
#pragma unroll
                for (int l = 0; l < 20; ++l) se1v[l] = bcast_(e1v, l);

                float fa = be2r, fb = 0.f;
#pragma unroll
                for (int k = 0; k < 10; ++k) {
                    fa = fmaf(we2r[2 * k],     se1v[2 * k],     fa);
                    fb = fmaf(we2r[2 * k + 1], se1v[2 * k + 1], fb);
                }
                float e2v = fmaxf(fa + fb, 0.f);

                float se2v[20];
#pragma unroll
                for (int l = 0; l < 20; ++l) se2v[l] = bcast_(e2v, l);

                float xa0 = be3A, xa1 = 0.f, xb0 = be3B, xb1 = 0.f;
#pragma unroll
                for (int l = 0; l < 10; ++l) {
                    xa0 = fmaf(we3A[2 * l],     se2v[2 * l],     xa0);
                    xa1 = fmaf(we3A[2 * l + 1], se2v[2 * l + 1], xa1);
                    xb0 = fmaf(we3B[2 * l],     se2v[2 * l],     xb0);
                    xb1 = fmaf(we3B[2 * l + 1], se2v[2 * l + 1], xb1);
                }
                float xA = sigmoidf_(xa0 + xa1);
                float xB = sigmoidf_(xb0 + xb1);
                if (lane < 50) {
                    int64_t ro = rowbase + (int64_t)(t - 1) * 100;
                    out[ro + lane]      = xA;               // fire-and-forget stores
                    out[ro + lane + 50] = xB;
                }
            }

            if (upd) {
#pragma unroll
                for (int k = 0; k < 10; ++k) g2p[k] = g2c[k];
#pragma unroll
                for (int k = 0; k < 10; ++k) g2c[k] = bcast_(h2keep, k);
            }
            BARRIER_SYNC();
        }
    }
}

extern "C" void kernel_launch(void* const* d_in, const int* in_sizes, int n_in,
                              void* d_out, int out_size, void* d_ws, size_t ws_size,
                              hipStream_t stream) {
    const float* mini_batch = (const float*)d_in[0];
    const float* eps        = (const float*)d_in[1];
    const float* W_ih1      = (const float*)d_in[2];
    const float* W_hh1      = (const float*)d_in[3];
    const float* b_ih1      = (const float*)d_in[4];
    const float* b_hh1      = (const float*)d_in[5];
    const float* W_ih2      = (const float*)d_in[6];
    const float* W_hh2      = (const float*)d_in[7];
    const float* b_ih2      = (const float*)d_in[8];
    const float* b_hh2      = (const float*)d_in[9];
    const float* h1_0       = (const float*)d_in[10];
    const float* h2_0       = (const float*)d_in[11];
    const float* Wt1        = (const float*)d_in[12];
    const float* bt1        = (const float*)d_in[13];
    const float* Wloc       = (const float*)d_in[14];
    const float* bloc       = (const float*)d_in[15];
    const float* Wsc        = (const float*)d_in[16];
    const float* bsc        = (const float*)d_in[17];
    const float* We1        = (const float*)d_in[18];
    const float* be1        = (const float*)d_in[19];
    const float* We2        = (const float*)d_in[20];
    const float* be2        = (const float*)d_in[21];
    const float* We3        = (const float*)d_in[22];
    const float* be3        = (const float*)d_in[23];
    float* out = (float*)d_out;

    // K1: gi2 precompute into out[.., 0:30] (scratch region, overwritten later by K2)
    gi2_kernel<<<(NB * T_LEN) / 64, 256, 0, stream>>>(mini_batch, W_ih2, b_ih2, out);

    // K2: sequential scan, one block per batch element
    scan_kernel<<<NB, 128, 0, stream>>>(eps, W_ih1, W_hh1, b_ih1, b_hh1, W_hh2, b_hh2,
                                        h1_0, h2_0, Wt1, bt1, Wloc, bloc, Wsc, bsc,
                                        We1, be1, We2, be2, We3, be3, out);
}